// Round 1
// baseline (997.532 us; speedup 1.0000x reference)
//
#include <hip/hip_runtime.h>
#include <math.h>

#define N_NODES 100000
#define N_EDGES 3200000

// ---------------------------------------------------------------------------
// fc1: h1 = relu(x @ W1 + b1)   x:[N,512] f32, W1:[512,16], h1:[N,16]
// Wave handles 4 rows. W1 transposed into LDS [16][512]; lane covers
// e = 4*lane..4*lane+3 and 256+4*lane..+3 (coalesced float4 x loads,
// <=2-way LDS bank aliasing on ds_read_b128). Pair-merge butterfly reduce:
// 17 shuffles/row, final value for dim (lane&15).
// ---------------------------------------------------------------------------
__global__ __launch_bounds__(256) void fc1_kernel(
    const float* __restrict__ x, const float* __restrict__ w,
    const float* __restrict__ b, float* __restrict__ h1) {
  __shared__ float wt[16][512];
  for (int idx = threadIdx.x; idx < 512 * 16; idx += 256) {
    int e = idx >> 4, o = idx & 15;
    wt[o][e] = w[idx];
  }
  __syncthreads();

  const int lane = threadIdx.x & 63;
  const int wid = blockIdx.x * 4 + (threadIdx.x >> 6);
  const int waves_total = gridDim.x * 4;
  const float bl = b[lane & 15];
  const int ngroups = N_NODES / 4;  // 25000, N divisible by 4

  for (int g = wid; g < ngroups; g += waves_total) {
    const int r0 = g * 4;
    float4 xa[4][2];
#pragma unroll
    for (int r = 0; r < 4; ++r) {
      const float4* xp = (const float4*)(x + (size_t)(r0 + r) * 512 + lane * 4);
      xa[r][0] = xp[0];
      xa[r][1] = xp[64];  // +256 floats
    }
    float acc[4][16];
#pragma unroll
    for (int r = 0; r < 4; ++r)
#pragma unroll
      for (int o = 0; o < 16; ++o) acc[r][o] = 0.f;

#pragma unroll
    for (int o = 0; o < 16; ++o) {
      const float4 w0 = *(const float4*)&wt[o][lane * 4];
      const float4 w1 = *(const float4*)&wt[o][256 + lane * 4];
#pragma unroll
      for (int r = 0; r < 4; ++r) {
        acc[r][o] += xa[r][0].x * w0.x + xa[r][0].y * w0.y +
                     xa[r][0].z * w0.z + xa[r][0].w * w0.w +
                     xa[r][1].x * w1.x + xa[r][1].y * w1.y +
                     xa[r][1].z * w1.z + xa[r][1].w * w1.w;
      }
    }

    const bool b0 = lane & 1, b1 = lane & 2, b2 = lane & 4, b3 = lane & 8;
#pragma unroll
    for (int r = 0; r < 4; ++r) {
      float v8[8];
#pragma unroll
      for (int j = 0; j < 8; ++j) {
        float keep = b0 ? acc[r][2 * j + 1] : acc[r][2 * j];
        float give = b0 ? acc[r][2 * j] : acc[r][2 * j + 1];
        v8[j] = keep + __shfl_xor(give, 1, 64);
      }
      float v4[4];
#pragma unroll
      for (int j = 0; j < 4; ++j) {
        float keep = b1 ? v8[2 * j + 1] : v8[2 * j];
        float give = b1 ? v8[2 * j] : v8[2 * j + 1];
        v4[j] = keep + __shfl_xor(give, 2, 64);
      }
      float v2[2];
#pragma unroll
      for (int j = 0; j < 2; ++j) {
        float keep = b2 ? v4[2 * j + 1] : v4[2 * j];
        float give = b2 ? v4[2 * j] : v4[2 * j + 1];
        v2[j] = keep + __shfl_xor(give, 4, 64);
      }
      float keep = b3 ? v2[1] : v2[0];
      float give = b3 ? v2[0] : v2[1];
      float v1 = keep + __shfl_xor(give, 8, 64);
      v1 += __shfl_xor(v1, 16, 64);
      v1 += __shfl_xor(v1, 32, 64);
      if (lane < 16) {
        h1[(size_t)(r0 + r) * 16 + lane] = fmaxf(v1 + bl, 0.f);
      }
    }
  }
}

// ---------------------------------------------------------------------------
// CSR build: count degrees, 3-kernel exclusive scan, atomic-cursor fill.
// ---------------------------------------------------------------------------
__global__ void count_kernel(const int* __restrict__ dst, int* __restrict__ cnt) {
  int idx = blockIdx.x * blockDim.x + threadIdx.x;
  int stride = gridDim.x * blockDim.x;
  for (int e = idx; e < N_EDGES; e += stride) atomicAdd(&cnt[dst[e]], 1);
}

__global__ __launch_bounds__(256) void scan1_kernel(
    const int* __restrict__ cnt, int* __restrict__ offs, int* __restrict__ bsums) {
  __shared__ int sm[256];
  const int bb = blockIdx.x, t = threadIdx.x;
  const int base = bb * 1024 + t * 4;
  int v[4];
#pragma unroll
  for (int j = 0; j < 4; ++j) v[j] = (base + j < N_NODES) ? cnt[base + j] : 0;
  const int s = v[0] + v[1] + v[2] + v[3];
  sm[t] = s;
  __syncthreads();
  for (int d = 1; d < 256; d <<= 1) {
    int add = (t >= d) ? sm[t - d] : 0;
    __syncthreads();
    sm[t] += add;
    __syncthreads();
  }
  const int excl = sm[t] - s;
  if (t == 255) bsums[bb] = sm[255];
  int p = excl;
#pragma unroll
  for (int j = 0; j < 4; ++j) {
    if (base + j < N_NODES) offs[base + j] = p;
    p += v[j];
  }
}

__global__ __launch_bounds__(128) void scan2_kernel(int* __restrict__ bsums, int nb) {
  __shared__ int sm[128];
  const int t = threadIdx.x;
  const int s = (t < nb) ? bsums[t] : 0;
  sm[t] = s;
  __syncthreads();
  for (int d = 1; d < 128; d <<= 1) {
    int add = (t >= d) ? sm[t - d] : 0;
    __syncthreads();
    sm[t] += add;
    __syncthreads();
  }
  if (t < nb) bsums[t] = sm[t] - s;  // exclusive block offsets
}

__global__ void scan3_kernel(int* __restrict__ offs, const int* __restrict__ bsums,
                             int* __restrict__ cur) {
  int i = blockIdx.x * blockDim.x + threadIdx.x;
  if (i >= N_NODES) return;
  int o = offs[i] + bsums[i >> 10];
  offs[i] = o;
  cur[i] = o;
}

__global__ void fill_kernel(const int* __restrict__ src, const int* __restrict__ dst,
                            int* __restrict__ cur, int* __restrict__ csr) {
  int idx = blockIdx.x * blockDim.x + threadIdx.x;
  int stride = gridDim.x * blockDim.x;
  for (int e = idx; e < N_EDGES; e += stride) {
    int d = dst[e];
    int p = atomicAdd(&cur[d], 1);
    csr[p] = src[e];
  }
}

// ---------------------------------------------------------------------------
// conv1: h2 = relu(mean_agg(h1) @ llw + llb + h1 @ lrw)   16 -> 32
// Thread-per-node gather over CSR; weights via uniform scalar loads.
// ---------------------------------------------------------------------------
__global__ __launch_bounds__(256) void conv1_kernel(
    const float* __restrict__ h1, const int* __restrict__ csr,
    const int* __restrict__ offs, const int* __restrict__ cnt,
    const float* __restrict__ llw, const float* __restrict__ llb,
    const float* __restrict__ lrw, float* __restrict__ h2) {
  int i = blockIdx.x * blockDim.x + threadIdx.x;
  if (i >= N_NODES) return;
  const int start = offs[i], deg = cnt[i];
  float acc[16];
#pragma unroll
  for (int k = 0; k < 16; ++k) acc[k] = 0.f;
  for (int e = 0; e < deg; ++e) {
    int s = csr[start + e];
    const float4* hp = (const float4*)(h1 + (size_t)s * 16);
    float4 a0 = hp[0], a1 = hp[1], a2 = hp[2], a3 = hp[3];
    acc[0] += a0.x; acc[1] += a0.y; acc[2] += a0.z; acc[3] += a0.w;
    acc[4] += a1.x; acc[5] += a1.y; acc[6] += a1.z; acc[7] += a1.w;
    acc[8] += a2.x; acc[9] += a2.y; acc[10] += a2.z; acc[11] += a2.w;
    acc[12] += a3.x; acc[13] += a3.y; acc[14] += a3.z; acc[15] += a3.w;
  }
  const float inv = 1.f / (float)(deg > 0 ? deg : 1);
#pragma unroll
  for (int k = 0; k < 16; ++k) acc[k] *= inv;
  const float4* sp = (const float4*)(h1 + (size_t)i * 16);
  float4 s0 = sp[0], s1 = sp[1], s2 = sp[2], s3 = sp[3];
  float self[16] = {s0.x, s0.y, s0.z, s0.w, s1.x, s1.y, s1.z, s1.w,
                    s2.x, s2.y, s2.z, s2.w, s3.x, s3.y, s3.z, s3.w};
  float out[32];
#pragma unroll
  for (int o = 0; o < 32; ++o) {
    float t = llb[o];
#pragma unroll
    for (int k = 0; k < 16; ++k)
      t += acc[k] * llw[k * 32 + o] + self[k] * lrw[k * 32 + o];
    out[o] = fmaxf(t, 0.f);
  }
  float4* op = (float4*)(h2 + (size_t)i * 32);
#pragma unroll
  for (int q = 0; q < 8; ++q)
    op[q] = make_float4(out[4 * q], out[4 * q + 1], out[4 * q + 2], out[4 * q + 3]);
}

// ---------------------------------------------------------------------------
// conv2 (32 -> 16) fused with fc2 (16 -> 3) + sigmoid/relu head -> d_out
// ---------------------------------------------------------------------------
__global__ __launch_bounds__(256) void conv2_kernel(
    const float* __restrict__ h2, const int* __restrict__ csr,
    const int* __restrict__ offs, const int* __restrict__ cnt,
    const float* __restrict__ llw, const float* __restrict__ llb,
    const float* __restrict__ lrw, const float* __restrict__ fc2w,
    const float* __restrict__ fc2b, float* __restrict__ out) {
  int i = blockIdx.x * blockDim.x + threadIdx.x;
  if (i >= N_NODES) return;
  const int start = offs[i], deg = cnt[i];
  float acc[32];
#pragma unroll
  for (int k = 0; k < 32; ++k) acc[k] = 0.f;
  for (int e = 0; e < deg; ++e) {
    int s = csr[start + e];
    const float4* hp = (const float4*)(h2 + (size_t)s * 32);
#pragma unroll
    for (int q = 0; q < 8; ++q) {
      float4 a = hp[q];
      acc[4 * q] += a.x; acc[4 * q + 1] += a.y;
      acc[4 * q + 2] += a.z; acc[4 * q + 3] += a.w;
    }
  }
  const float inv = 1.f / (float)(deg > 0 ? deg : 1);
#pragma unroll
  for (int k = 0; k < 32; ++k) acc[k] *= inv;
  float self[32];
  const float4* sp = (const float4*)(h2 + (size_t)i * 32);
#pragma unroll
  for (int q = 0; q < 8; ++q) {
    float4 a = sp[q];
    self[4 * q] = a.x; self[4 * q + 1] = a.y;
    self[4 * q + 2] = a.z; self[4 * q + 3] = a.w;
  }
  float f[16];
#pragma unroll
  for (int o = 0; o < 16; ++o) {
    float t = llb[o];
#pragma unroll
    for (int k = 0; k < 32; ++k)
      t += acc[k] * llw[k * 16 + o] + self[k] * lrw[k * 16 + o];
    f[o] = fmaxf(t, 0.f);
  }
  float v[3];
#pragma unroll
  for (int j = 0; j < 3; ++j) {
    float t = fc2b[j];
#pragma unroll
    for (int k = 0; k < 16; ++k) t += f[k] * fc2w[k * 3 + j];
    v[j] = t;
  }
  float gsi = 1.f / (1.f + expf(-v[1]));
  float mxi = 1.f / (1.f + expf(-v[2]));
  float fsi = fmaxf(v[0], 0.f) + gsi;
  out[(size_t)i * 3 + 0] = fsi;
  out[(size_t)i * 3 + 1] = gsi;
  out[(size_t)i * 3 + 2] = mxi;
}

extern "C" void kernel_launch(void* const* d_in, const int* in_sizes, int n_in,
                              void* d_out, int out_size, void* d_ws, size_t ws_size,
                              hipStream_t stream) {
  const float* x = (const float*)d_in[0];
  const int* ei = (const int*)d_in[1];
  const float* fc1w = (const float*)d_in[2];
  const float* fc1b = (const float*)d_in[3];
  const float* c1llw = (const float*)d_in[4];
  const float* c1llb = (const float*)d_in[5];
  const float* c1lrw = (const float*)d_in[6];
  const float* c2llw = (const float*)d_in[7];
  const float* c2llb = (const float*)d_in[8];
  const float* c2lrw = (const float*)d_in[9];
  const float* fc2w = (const float*)d_in[10];
  const float* fc2b = (const float*)d_in[11];
  float* outp = (float*)d_out;
  const int* src = ei;
  const int* dst = ei + N_EDGES;

  char* ws = (char*)d_ws;
  float* h1 = (float*)ws;   ws += (size_t)N_NODES * 16 * 4;
  float* h2 = (float*)ws;   ws += (size_t)N_NODES * 32 * 4;
  int* cnt = (int*)ws;      ws += (size_t)N_NODES * 4;
  int* offs = (int*)ws;     ws += (size_t)N_NODES * 4;
  int* cur = (int*)ws;      ws += (size_t)N_NODES * 4;
  int* csr = (int*)ws;      ws += (size_t)N_EDGES * 4;
  int* bsums = (int*)ws;    ws += 256 * 4;
  (void)ws_size; (void)n_in; (void)in_sizes; (void)out_size;

  hipMemsetAsync(cnt, 0, (size_t)N_NODES * 4, stream);
  fc1_kernel<<<512, 256, 0, stream>>>(x, fc1w, fc1b, h1);
  count_kernel<<<2048, 256, 0, stream>>>(dst, cnt);
  scan1_kernel<<<98, 256, 0, stream>>>(cnt, offs, bsums);
  scan2_kernel<<<1, 128, 0, stream>>>(bsums, 98);
  scan3_kernel<<<(N_NODES + 255) / 256, 256, 0, stream>>>(offs, bsums, cur);
  fill_kernel<<<2048, 256, 0, stream>>>(src, dst, cur, csr);
  conv1_kernel<<<(N_NODES + 255) / 256, 256, 0, stream>>>(h1, csr, offs, cnt,
                                                          c1llw, c1llb, c1lrw, h2);
  conv2_kernel<<<(N_NODES + 255) / 256, 256, 0, stream>>>(h2, csr, offs, cnt,
                                                          c2llw, c2llb, c2lrw,
                                                          fc2w, fc2b, outp);
}

// Round 2
// 620.419 us; speedup vs baseline: 1.6078x; 1.6078x over previous
//
#include <hip/hip_runtime.h>
#include <math.h>

#define N_NODES 100000
#define N_EDGES 3200000

// ---------------------------------------------------------------------------
// fc1: h1 = relu(x @ W1 + b1)   x:[N,512] f32, W1:[512,16], h1:[N,16]
// Wave handles 4 rows; W1 transposed in LDS; pair-merge butterfly reduce.
// ---------------------------------------------------------------------------
__global__ __launch_bounds__(256) void fc1_kernel(
    const float* __restrict__ x, const float* __restrict__ w,
    const float* __restrict__ b, float* __restrict__ h1) {
  __shared__ float wt[16][512];
  for (int idx = threadIdx.x; idx < 512 * 16; idx += 256) {
    int e = idx >> 4, o = idx & 15;
    wt[o][e] = w[idx];
  }
  __syncthreads();

  const int lane = threadIdx.x & 63;
  const int wid = blockIdx.x * 4 + (threadIdx.x >> 6);
  const int waves_total = gridDim.x * 4;
  const float bl = b[lane & 15];
  const int ngroups = N_NODES / 4;  // 25000

  for (int g = wid; g < ngroups; g += waves_total) {
    const int r0 = g * 4;
    float4 xa[4][2];
#pragma unroll
    for (int r = 0; r < 4; ++r) {
      const float4* xp = (const float4*)(x + (size_t)(r0 + r) * 512 + lane * 4);
      xa[r][0] = xp[0];
      xa[r][1] = xp[64];
    }
    float acc[4][16];
#pragma unroll
    for (int r = 0; r < 4; ++r)
#pragma unroll
      for (int o = 0; o < 16; ++o) acc[r][o] = 0.f;

#pragma unroll
    for (int o = 0; o < 16; ++o) {
      const float4 w0 = *(const float4*)&wt[o][lane * 4];
      const float4 w1 = *(const float4*)&wt[o][256 + lane * 4];
#pragma unroll
      for (int r = 0; r < 4; ++r) {
        acc[r][o] += xa[r][0].x * w0.x + xa[r][0].y * w0.y +
                     xa[r][0].z * w0.z + xa[r][0].w * w0.w +
                     xa[r][1].x * w1.x + xa[r][1].y * w1.y +
                     xa[r][1].z * w1.z + xa[r][1].w * w1.w;
      }
    }

    const bool b0 = lane & 1, b1 = lane & 2, b2 = lane & 4, b3 = lane & 8;
#pragma unroll
    for (int r = 0; r < 4; ++r) {
      float v8[8];
#pragma unroll
      for (int j = 0; j < 8; ++j) {
        float keep = b0 ? acc[r][2 * j + 1] : acc[r][2 * j];
        float give = b0 ? acc[r][2 * j] : acc[r][2 * j + 1];
        v8[j] = keep + __shfl_xor(give, 1, 64);
      }
      float v4[4];
#pragma unroll
      for (int j = 0; j < 4; ++j) {
        float keep = b1 ? v8[2 * j + 1] : v8[2 * j];
        float give = b1 ? v8[2 * j] : v8[2 * j + 1];
        v4[j] = keep + __shfl_xor(give, 2, 64);
      }
      float v2[2];
#pragma unroll
      for (int j = 0; j < 2; ++j) {
        float keep = b2 ? v4[2 * j + 1] : v4[2 * j];
        float give = b2 ? v4[2 * j] : v4[2 * j + 1];
        v2[j] = keep + __shfl_xor(give, 4, 64);
      }
      float keep = b3 ? v2[1] : v2[0];
      float give = b3 ? v2[0] : v2[1];
      float v1 = keep + __shfl_xor(give, 8, 64);
      v1 += __shfl_xor(v1, 16, 64);
      v1 += __shfl_xor(v1, 32, 64);
      if (lane < 16) {
        h1[(size_t)(r0 + r) * 16 + lane] = fmaxf(v1 + bl, 0.f);
      }
    }
  }
}

// ---------------------------------------------------------------------------
// CSR build
// ---------------------------------------------------------------------------
__global__ void count_kernel(const int* __restrict__ dst, int* __restrict__ cnt) {
  int idx = blockIdx.x * blockDim.x + threadIdx.x;
  int stride = gridDim.x * blockDim.x;
  for (int e = idx; e < N_EDGES; e += stride) atomicAdd(&cnt[dst[e]], 1);
}

__global__ __launch_bounds__(256) void scan1_kernel(
    const int* __restrict__ cnt, int* __restrict__ offs, int* __restrict__ bsums) {
  __shared__ int sm[256];
  const int bb = blockIdx.x, t = threadIdx.x;
  const int base = bb * 1024 + t * 4;
  int v[4];
#pragma unroll
  for (int j = 0; j < 4; ++j) v[j] = (base + j < N_NODES) ? cnt[base + j] : 0;
  const int s = v[0] + v[1] + v[2] + v[3];
  sm[t] = s;
  __syncthreads();
  for (int d = 1; d < 256; d <<= 1) {
    int add = (t >= d) ? sm[t - d] : 0;
    __syncthreads();
    sm[t] += add;
    __syncthreads();
  }
  const int excl = sm[t] - s;
  if (t == 255) bsums[bb] = sm[255];
  int p = excl;
#pragma unroll
  for (int j = 0; j < 4; ++j) {
    if (base + j < N_NODES) offs[base + j] = p;
    p += v[j];
  }
}

__global__ __launch_bounds__(128) void scan2_kernel(int* __restrict__ bsums, int nb) {
  __shared__ int sm[128];
  const int t = threadIdx.x;
  const int s = (t < nb) ? bsums[t] : 0;
  sm[t] = s;
  __syncthreads();
  for (int d = 1; d < 128; d <<= 1) {
    int add = (t >= d) ? sm[t - d] : 0;
    __syncthreads();
    sm[t] += add;
    __syncthreads();
  }
  if (t < nb) bsums[t] = sm[t] - s;
}

__global__ void scan3_kernel(int* __restrict__ offs, const int* __restrict__ bsums,
                             int* __restrict__ cur) {
  int i = blockIdx.x * blockDim.x + threadIdx.x;
  if (i >= N_NODES) return;
  int o = offs[i] + bsums[i >> 10];
  offs[i] = o;
  cur[i] = o;
}

__global__ void fill_kernel(const int* __restrict__ src, const int* __restrict__ dst,
                            int* __restrict__ cur, int* __restrict__ csr) {
  int idx = blockIdx.x * blockDim.x + threadIdx.x;
  int stride = gridDim.x * blockDim.x;
  for (int e = idx; e < N_EDGES; e += stride) {
    int d = dst[e];
    int p = atomicAdd(&cur[d], 1);
    csr[p] = src[e];
  }
}

// ---------------------------------------------------------------------------
// conv1: h2 = relu(mean_agg(h1) @ llw + llb + h1 @ lrw)   16 -> 32
// 4 threads per node; thread t owns input-dims [4t..4t+3]. Coalesced 64B
// row gathers across the 4-lane group. Partial matmul on k-slice, butterfly
// reduce (masks 1,2) -> every lane has all 32 sums; lane writes dims
// [8t..8t+7].
// ---------------------------------------------------------------------------
__global__ __launch_bounds__(256) void conv1_kernel(
    const float* __restrict__ h1, const int* __restrict__ csr,
    const int* __restrict__ offs, const int* __restrict__ cnt,
    const float* __restrict__ llw, const float* __restrict__ llb,
    const float* __restrict__ lrw, float* __restrict__ h2) {
  __shared__ float wl[16 * 32];
  __shared__ float wr[16 * 32];
  __shared__ float bbias[32];
  for (int idx = threadIdx.x; idx < 512; idx += 256) {
    wl[idx] = llw[idx];
    wr[idx] = lrw[idx];
  }
  if (threadIdx.x < 32) bbias[threadIdx.x] = llb[threadIdx.x];
  __syncthreads();

  const int tid = blockIdx.x * 256 + threadIdx.x;
  const int i = tid >> 2;
  if (i >= N_NODES) return;
  const int t = threadIdx.x & 3;
  const int start = offs[i], deg = cnt[i];

  float4 acc = make_float4(0.f, 0.f, 0.f, 0.f);
  for (int e = 0; e < deg; ++e) {
    int s = csr[start + e];
    float4 a = *(const float4*)(h1 + (size_t)s * 16 + t * 4);
    acc.x += a.x; acc.y += a.y; acc.z += a.z; acc.w += a.w;
  }
  const float inv = 1.f / (float)(deg > 0 ? deg : 1);
  const float4 self = *(const float4*)(h1 + (size_t)i * 16 + t * 4);
  const float mk[4] = {acc.x * inv, acc.y * inv, acc.z * inv, acc.w * inv};
  const float sk[4] = {self.x, self.y, self.z, self.w};

  float4 p[8];
#pragma unroll
  for (int q = 0; q < 8; ++q) p[q] = make_float4(0.f, 0.f, 0.f, 0.f);
#pragma unroll
  for (int j = 0; j < 4; ++j) {
    const int k = 4 * t + j;
#pragma unroll
    for (int q = 0; q < 8; ++q) {
      float4 w4l = *(const float4*)&wl[k * 32 + 4 * q];
      float4 w4r = *(const float4*)&wr[k * 32 + 4 * q];
      p[q].x += mk[j] * w4l.x + sk[j] * w4r.x;
      p[q].y += mk[j] * w4l.y + sk[j] * w4r.y;
      p[q].z += mk[j] * w4l.z + sk[j] * w4r.z;
      p[q].w += mk[j] * w4l.w + sk[j] * w4r.w;
    }
  }
#pragma unroll
  for (int mask = 1; mask <= 2; mask <<= 1) {
#pragma unroll
    for (int q = 0; q < 8; ++q) {
      p[q].x += __shfl_xor(p[q].x, mask, 64);
      p[q].y += __shfl_xor(p[q].y, mask, 64);
      p[q].z += __shfl_xor(p[q].z, mask, 64);
      p[q].w += __shfl_xor(p[q].w, mask, 64);
    }
  }
  // lane t writes output quads q = 2t, 2t+1
#pragma unroll
  for (int m = 0; m < 2; ++m) {
    const int q = 2 * t + m;
    float4 v = p[q];
    v.x = fmaxf(v.x + bbias[4 * q + 0], 0.f);
    v.y = fmaxf(v.y + bbias[4 * q + 1], 0.f);
    v.z = fmaxf(v.z + bbias[4 * q + 2], 0.f);
    v.w = fmaxf(v.w + bbias[4 * q + 3], 0.f);
    *(float4*)(h2 + (size_t)i * 32 + 4 * q) = v;
  }
}

// ---------------------------------------------------------------------------
// conv2 (32 -> 16) fused with fc2 (16 -> 3) + head -> d_out
// 8 threads per node; thread t owns input-dims [4t..4t+3]. The 8-lane group
// covers the full 128B row per edge -> fully coalesced gather. Butterfly
// reduce (masks 1,2,4) -> every lane has f[16]; lanes 0..2 emit the head.
// ---------------------------------------------------------------------------
__global__ __launch_bounds__(256) void conv2_kernel(
    const float* __restrict__ h2, const int* __restrict__ csr,
    const int* __restrict__ offs, const int* __restrict__ cnt,
    const float* __restrict__ llw, const float* __restrict__ llb,
    const float* __restrict__ lrw, const float* __restrict__ fc2w,
    const float* __restrict__ fc2b, float* __restrict__ out) {
  __shared__ float wl[32 * 16];
  __shared__ float wr[32 * 16];
  __shared__ float bbias[16];
  __shared__ float w2[48];
  __shared__ float b2[3];
  for (int idx = threadIdx.x; idx < 512; idx += 256) {
    wl[idx] = llw[idx];
    wr[idx] = lrw[idx];
  }
  if (threadIdx.x < 16) bbias[threadIdx.x] = llb[threadIdx.x];
  else if (threadIdx.x >= 64 && threadIdx.x < 112) w2[threadIdx.x - 64] = fc2w[threadIdx.x - 64];
  else if (threadIdx.x >= 128 && threadIdx.x < 131) b2[threadIdx.x - 128] = fc2b[threadIdx.x - 128];
  __syncthreads();

  const int tid = blockIdx.x * 256 + threadIdx.x;
  const int i = tid >> 3;
  if (i >= N_NODES) return;
  const int t = threadIdx.x & 7;
  const int start = offs[i], deg = cnt[i];

  float4 acc = make_float4(0.f, 0.f, 0.f, 0.f);
  for (int e = 0; e < deg; ++e) {
    int s = csr[start + e];
    float4 a = *(const float4*)(h2 + (size_t)s * 32 + t * 4);
    acc.x += a.x; acc.y += a.y; acc.z += a.z; acc.w += a.w;
  }
  const float inv = 1.f / (float)(deg > 0 ? deg : 1);
  const float4 self = *(const float4*)(h2 + (size_t)i * 32 + t * 4);
  const float mk[4] = {acc.x * inv, acc.y * inv, acc.z * inv, acc.w * inv};
  const float sk[4] = {self.x, self.y, self.z, self.w};

  float4 p[4];
#pragma unroll
  for (int q = 0; q < 4; ++q) p[q] = make_float4(0.f, 0.f, 0.f, 0.f);
#pragma unroll
  for (int j = 0; j < 4; ++j) {
    const int k = 4 * t + j;
#pragma unroll
    for (int q = 0; q < 4; ++q) {
      float4 w4l = *(const float4*)&wl[k * 16 + 4 * q];
      float4 w4r = *(const float4*)&wr[k * 16 + 4 * q];
      p[q].x += mk[j] * w4l.x + sk[j] * w4r.x;
      p[q].y += mk[j] * w4l.y + sk[j] * w4r.y;
      p[q].z += mk[j] * w4l.z + sk[j] * w4r.z;
      p[q].w += mk[j] * w4l.w + sk[j] * w4r.w;
    }
  }
#pragma unroll
  for (int mask = 1; mask <= 4; mask <<= 1) {
#pragma unroll
    for (int q = 0; q < 4; ++q) {
      p[q].x += __shfl_xor(p[q].x, mask, 64);
      p[q].y += __shfl_xor(p[q].y, mask, 64);
      p[q].z += __shfl_xor(p[q].z, mask, 64);
      p[q].w += __shfl_xor(p[q].w, mask, 64);
    }
  }
  float f[16];
#pragma unroll
  for (int q = 0; q < 4; ++q) {
    f[4 * q + 0] = fmaxf(p[q].x + bbias[4 * q + 0], 0.f);
    f[4 * q + 1] = fmaxf(p[q].y + bbias[4 * q + 1], 0.f);
    f[4 * q + 2] = fmaxf(p[q].z + bbias[4 * q + 2], 0.f);
    f[4 * q + 3] = fmaxf(p[q].w + bbias[4 * q + 3], 0.f);
  }
  if (t < 3) {
    float v0 = b2[0], v1 = b2[1], v2 = b2[2];
#pragma unroll
    for (int k = 0; k < 16; ++k) {
      v0 += f[k] * w2[k * 3 + 0];
      v1 += f[k] * w2[k * 3 + 1];
      v2 += f[k] * w2[k * 3 + 2];
    }
    float gsi = 1.f / (1.f + expf(-v1));
    float mxi = 1.f / (1.f + expf(-v2));
    float fsi = fmaxf(v0, 0.f) + gsi;
    float rv = (t == 0) ? fsi : ((t == 1) ? gsi : mxi);
    out[(size_t)i * 3 + t] = rv;
  }
}

extern "C" void kernel_launch(void* const* d_in, const int* in_sizes, int n_in,
                              void* d_out, int out_size, void* d_ws, size_t ws_size,
                              hipStream_t stream) {
  const float* x = (const float*)d_in[0];
  const int* ei = (const int*)d_in[1];
  const float* fc1w = (const float*)d_in[2];
  const float* fc1b = (const float*)d_in[3];
  const float* c1llw = (const float*)d_in[4];
  const float* c1llb = (const float*)d_in[5];
  const float* c1lrw = (const float*)d_in[6];
  const float* c2llw = (const float*)d_in[7];
  const float* c2llb = (const float*)d_in[8];
  const float* c2lrw = (const float*)d_in[9];
  const float* fc2w = (const float*)d_in[10];
  const float* fc2b = (const float*)d_in[11];
  float* outp = (float*)d_out;
  const int* src = ei;
  const int* dst = ei + N_EDGES;

  char* ws = (char*)d_ws;
  float* h1 = (float*)ws;   ws += (size_t)N_NODES * 16 * 4;
  float* h2 = (float*)ws;   ws += (size_t)N_NODES * 32 * 4;
  int* cnt = (int*)ws;      ws += (size_t)N_NODES * 4;
  int* offs = (int*)ws;     ws += (size_t)N_NODES * 4;
  int* cur = (int*)ws;      ws += (size_t)N_NODES * 4;
  int* csr = (int*)ws;      ws += (size_t)N_EDGES * 4;
  int* bsums = (int*)ws;    ws += 256 * 4;
  (void)ws_size; (void)n_in; (void)in_sizes; (void)out_size;

  hipMemsetAsync(cnt, 0, (size_t)N_NODES * 4, stream);
  fc1_kernel<<<512, 256, 0, stream>>>(x, fc1w, fc1b, h1);
  count_kernel<<<2048, 256, 0, stream>>>(dst, cnt);
  scan1_kernel<<<98, 256, 0, stream>>>(cnt, offs, bsums);
  scan2_kernel<<<1, 128, 0, stream>>>(bsums, 98);
  scan3_kernel<<<(N_NODES + 255) / 256, 256, 0, stream>>>(offs, bsums, cur);
  fill_kernel<<<2048, 256, 0, stream>>>(src, dst, cur, csr);
  conv1_kernel<<<(N_NODES * 4 + 255) / 256, 256, 0, stream>>>(h1, csr, offs, cnt,
                                                              c1llw, c1llb, c1lrw, h2);
  conv2_kernel<<<(N_NODES * 8 + 255) / 256, 256, 0, stream>>>(h2, csr, offs, cnt,
                                                              c2llw, c2llb, c2lrw,
                                                              fc2w, fc2b, outp);
}